// Round 2
// baseline (343.551 us; speedup 1.0000x reference)
//
#include <hip/hip_runtime.h>
#include <cmath>
#include <cstdint>

#define NLEVELS 16
#define LOG2T 19
#define TSIZE (1u << LOG2T)

struct ResTable { float r[NLEVELS]; };

// ---------------------------------------------------------------------------
// Kernel 1: hash encode. One thread per (point, level-pair).
// blockIdx.x % 8 == level-pair -> pins each pair's table slice to one XCD's L2
// (measured round-robin block->XCD mapping; perf heuristic only).
// Output: embT[pair][point][4] floats (levels 2p,2p+1 x features f0,f1).
// ---------------------------------------------------------------------------
__global__ __launch_bounds__(256) void ngp_encode(
    const float* __restrict__ x,      // (N,3)
    const float* __restrict__ table,  // (L,T,2)
    float* __restrict__ embT,         // (8, N, 4)
    ResTable res, int n)
{
    int pair  = blockIdx.x & 7;
    int chunk = blockIdx.x >> 3;
    int i = chunk * 256 + threadIdx.x;
    if (i >= n) return;

    float xn0 = x[3 * i + 0] + 0.5f;
    float xn1 = x[3 * i + 1] + 0.5f;
    float xn2 = x[3 * i + 2] + 0.5f;

    // compute all 16 hash indices + weights first, then issue all 16 loads,
    // then accumulate -- maximizes outstanding VMEM per wave.
    uint32_t hidx[16];
    float    wgt[16];
    const float* tbase[2];

    #pragma unroll
    for (int ll = 0; ll < 2; ++ll) {
        int l = pair * 2 + ll;
        float r  = res.r[l];
        float p0 = xn0 * r, p1 = xn1 * r, p2 = xn2 * r;
        float f0 = floorf(p0), f1 = floorf(p1), f2 = floorf(p2);
        float fr0 = p0 - f0, fr1 = p1 - f1, fr2 = p2 - f2;
        uint32_t xi0 = (uint32_t)f0, xi1 = (uint32_t)f1, xi2 = (uint32_t)f2;
        uint32_t hx0 = xi0,               hx1 = xi0 + 1u;
        uint32_t hy0 = xi1 * 2654435761u, hy1 = (xi1 + 1u) * 2654435761u;
        uint32_t hz0 = xi2 * 805459861u,  hz1 = (xi2 + 1u) * 805459861u;
        tbase[ll] = table + (size_t)l * (size_t)TSIZE * 2u;
        #pragma unroll
        for (int c = 0; c < 8; ++c) {
            uint32_t hx = (c & 4) ? hx1 : hx0;
            uint32_t hy = (c & 2) ? hy1 : hy0;
            uint32_t hz = (c & 1) ? hz1 : hz0;
            hidx[ll * 8 + c] = (hx ^ hy ^ hz) & (TSIZE - 1u);
            float wx = (c & 4) ? fr0 : 1.f - fr0;
            float wy = (c & 2) ? fr1 : 1.f - fr1;
            float wz = (c & 1) ? fr2 : 1.f - fr2;
            wgt[ll * 8 + c] = wx * wy * wz;
        }
    }

    float2 v[16];
    #pragma unroll
    for (int ll = 0; ll < 2; ++ll)
        #pragma unroll
        for (int c = 0; c < 8; ++c)
            v[ll * 8 + c] = *reinterpret_cast<const float2*>(
                                tbase[ll] + 2u * hidx[ll * 8 + c]);

    float4 o;
    float a00 = 0.f, a01 = 0.f, a10 = 0.f, a11 = 0.f;
    #pragma unroll
    for (int c = 0; c < 8; ++c) {
        a00 = fmaf(wgt[c],     v[c].x,     a00);
        a01 = fmaf(wgt[c],     v[c].y,     a01);
        a10 = fmaf(wgt[8 + c], v[8 + c].x, a10);
        a11 = fmaf(wgt[8 + c], v[8 + c].y, a11);
    }
    o.x = a00; o.y = a01; o.z = a10; o.w = a11;
    *reinterpret_cast<float4*>(embT + ((size_t)pair * n + i) * 4u) = o;
}

// ---------------------------------------------------------------------------
// Kernel 2: SH encode + MLPs. One thread per point, pure VALU.
// ---------------------------------------------------------------------------
__global__ __launch_bounds__(256) void ngp_mlp(
    const float* __restrict__ embT,     // (8, N, 4)
    const float* __restrict__ d,        // (N,3)
    const float* __restrict__ xyz_w0,   // (64,32)
    const float* __restrict__ xyz_wout, // (16,64)
    const float* __restrict__ rgb_w0,   // (64,32)
    const float* __restrict__ rgb_w1,   // (64,64)
    const float* __restrict__ rgb_wout, // (3,64)
    float* __restrict__ out,            // [N] sigma then [N*3] rgb
    int n)
{
    int i = blockIdx.x * blockDim.x + threadIdx.x;
    if (i >= n) return;

    float emb[32];
    #pragma unroll
    for (int p = 0; p < 8; ++p) {
        float4 v = *reinterpret_cast<const float4*>(embT + ((size_t)p * n + i) * 4u);
        emb[4 * p + 0] = v.x; emb[4 * p + 1] = v.y;
        emb[4 * p + 2] = v.z; emb[4 * p + 3] = v.w;
    }

    // xyz MLP: 32 -> 64 (ReLU) -> 16
    float h1[64];
    #pragma unroll
    for (int j = 0; j < 64; ++j) {
        float s = 0.f;
        #pragma unroll
        for (int k = 0; k < 32; ++k) s = fmaf(emb[k], xyz_w0[j * 32 + k], s);
        h1[j] = fmaxf(s, 0.f);
    }
    float hh[16];
    #pragma unroll
    for (int o = 0; o < 16; ++o) {
        float s = 0.f;
        #pragma unroll
        for (int k = 0; k < 64; ++k) s = fmaf(h1[k], xyz_wout[o * 64 + k], s);
        hh[o] = s;
    }
    out[i] = expf(hh[0]);   // sigma

    // SH degree-4
    float dx = d[3 * i + 0], dy = d[3 * i + 1], dz = d[3 * i + 2];
    float inv = rsqrtf(dx * dx + dy * dy + dz * dz);
    float X = dx * inv, Y = dy * inv, Z = dz * inv;
    float xx = X * X, yy = Y * Y, zz = Z * Z;
    float xy = X * Y, yz = Y * Z, xz = X * Z;

    float f[32];
    f[0]  = 0.28209479177387814f;
    f[1]  = -0.4886025119029199f * Y;
    f[2]  =  0.4886025119029199f * Z;
    f[3]  = -0.4886025119029199f * X;
    f[4]  =  1.0925484305920792f * xy;
    f[5]  = -1.0925484305920792f * yz;
    f[6]  =  0.31539156525252005f * (3.0f * zz - 1.0f);
    f[7]  = -1.0925484305920792f * xz;
    f[8]  =  0.5462742152960396f * (xx - yy);
    f[9]  = -0.5900435899266435f * Y * (3.0f * xx - yy);
    f[10] =  2.890611442640554f * xy * Z;
    f[11] = -0.4570457994644658f * Y * (4.0f * zz - xx - yy);
    f[12] =  0.3731763325901154f * Z * (2.0f * zz - 3.0f * xx - 3.0f * yy);
    f[13] = -0.4570457994644658f * X * (4.0f * zz - xx - yy);
    f[14] =  1.445305721320277f * Z * (xx - yy);
    f[15] = -0.5900435899266435f * X * (xx - 3.0f * yy);
    #pragma unroll
    for (int o = 0; o < 16; ++o) f[16 + o] = hh[o];

    // rgb MLP: 32 -> 64 (ReLU) -> 64 (ReLU) -> 3 (sigmoid)
    float b1[64];
    #pragma unroll
    for (int j = 0; j < 64; ++j) {
        float s = 0.f;
        #pragma unroll
        for (int k = 0; k < 32; ++k) s = fmaf(f[k], rgb_w0[j * 32 + k], s);
        b1[j] = fmaxf(s, 0.f);
    }
    float b2[64];
    #pragma unroll
    for (int j = 0; j < 64; ++j) {
        float s = 0.f;
        #pragma unroll
        for (int k = 0; k < 64; ++k) s = fmaf(b1[k], rgb_w1[j * 64 + k], s);
        b2[j] = fmaxf(s, 0.f);
    }
    #pragma unroll
    for (int o = 0; o < 3; ++o) {
        float s = 0.f;
        #pragma unroll
        for (int k = 0; k < 64; ++k) s = fmaf(b2[k], rgb_wout[o * 64 + k], s);
        out[n + 3 * i + o] = 1.0f / (1.0f + expf(-s));
    }
}

// ---------------------------------------------------------------------------
// Fallback: round-1 fused kernel (used only if ws is too small for emb).
// ---------------------------------------------------------------------------
__global__ __launch_bounds__(256) void ngp_fused(
    const float* __restrict__ x,
    const float* __restrict__ d,
    const float* __restrict__ table,
    const float* __restrict__ xyz_w0,
    const float* __restrict__ xyz_wout,
    const float* __restrict__ rgb_w0,
    const float* __restrict__ rgb_w1,
    const float* __restrict__ rgb_wout,
    float* __restrict__ out,
    ResTable res, int n)
{
    int i = blockIdx.x * blockDim.x + threadIdx.x;
    if (i >= n) return;

    float xn0 = x[3 * i + 0] + 0.5f;
    float xn1 = x[3 * i + 1] + 0.5f;
    float xn2 = x[3 * i + 2] + 0.5f;

    float emb[NLEVELS * 2];
    #pragma unroll
    for (int l = 0; l < NLEVELS; ++l) {
        float r  = res.r[l];
        float p0 = xn0 * r, p1 = xn1 * r, p2 = xn2 * r;
        float f0 = floorf(p0), f1 = floorf(p1), f2 = floorf(p2);
        float fr0 = p0 - f0, fr1 = p1 - f1, fr2 = p2 - f2;
        uint32_t xi0 = (uint32_t)f0, xi1 = (uint32_t)f1, xi2 = (uint32_t)f2;
        uint32_t hx0 = xi0,               hx1 = xi0 + 1u;
        uint32_t hy0 = xi1 * 2654435761u, hy1 = (xi1 + 1u) * 2654435761u;
        uint32_t hz0 = xi2 * 805459861u,  hz1 = (xi2 + 1u) * 805459861u;
        const float* tl = table + (size_t)l * (size_t)TSIZE * 2u;
        float acc0 = 0.f, acc1 = 0.f;
        #pragma unroll
        for (int c = 0; c < 8; ++c) {
            uint32_t hx = (c & 4) ? hx1 : hx0;
            uint32_t hy = (c & 2) ? hy1 : hy0;
            uint32_t hz = (c & 1) ? hz1 : hz0;
            uint32_t h  = (hx ^ hy ^ hz) & (TSIZE - 1u);
            float wx = (c & 4) ? fr0 : 1.f - fr0;
            float wy = (c & 2) ? fr1 : 1.f - fr1;
            float wz = (c & 1) ? fr2 : 1.f - fr2;
            float w  = wx * wy * wz;
            float2 v = *reinterpret_cast<const float2*>(tl + 2u * h);
            acc0 = fmaf(w, v.x, acc0);
            acc1 = fmaf(w, v.y, acc1);
        }
        emb[2 * l]     = acc0;
        emb[2 * l + 1] = acc1;
    }

    float h1[64];
    #pragma unroll
    for (int j = 0; j < 64; ++j) {
        float s = 0.f;
        #pragma unroll
        for (int k = 0; k < 32; ++k) s = fmaf(emb[k], xyz_w0[j * 32 + k], s);
        h1[j] = fmaxf(s, 0.f);
    }
    float hh[16];
    #pragma unroll
    for (int o = 0; o < 16; ++o) {
        float s = 0.f;
        #pragma unroll
        for (int k = 0; k < 64; ++k) s = fmaf(h1[k], xyz_wout[o * 64 + k], s);
        hh[o] = s;
    }
    out[i] = expf(hh[0]);

    float dx = d[3 * i + 0], dy = d[3 * i + 1], dz = d[3 * i + 2];
    float inv = rsqrtf(dx * dx + dy * dy + dz * dz);
    float X = dx * inv, Y = dy * inv, Z = dz * inv;
    float xx = X * X, yy = Y * Y, zz = Z * Z;
    float xy = X * Y, yz = Y * Z, xz = X * Z;

    float f[32];
    f[0]  = 0.28209479177387814f;
    f[1]  = -0.4886025119029199f * Y;
    f[2]  =  0.4886025119029199f * Z;
    f[3]  = -0.4886025119029199f * X;
    f[4]  =  1.0925484305920792f * xy;
    f[5]  = -1.0925484305920792f * yz;
    f[6]  =  0.31539156525252005f * (3.0f * zz - 1.0f);
    f[7]  = -1.0925484305920792f * xz;
    f[8]  =  0.5462742152960396f * (xx - yy);
    f[9]  = -0.5900435899266435f * Y * (3.0f * xx - yy);
    f[10] =  2.890611442640554f * xy * Z;
    f[11] = -0.4570457994644658f * Y * (4.0f * zz - xx - yy);
    f[12] =  0.3731763325901154f * Z * (2.0f * zz - 3.0f * xx - 3.0f * yy);
    f[13] = -0.4570457994644658f * X * (4.0f * zz - xx - yy);
    f[14] =  1.445305721320277f * Z * (xx - yy);
    f[15] = -0.5900435899266435f * X * (xx - 3.0f * yy);
    #pragma unroll
    for (int o = 0; o < 16; ++o) f[16 + o] = hh[o];

    float b1[64];
    #pragma unroll
    for (int j = 0; j < 64; ++j) {
        float s = 0.f;
        #pragma unroll
        for (int k = 0; k < 32; ++k) s = fmaf(f[k], rgb_w0[j * 32 + k], s);
        b1[j] = fmaxf(s, 0.f);
    }
    float b2[64];
    #pragma unroll
    for (int j = 0; j < 64; ++j) {
        float s = 0.f;
        #pragma unroll
        for (int k = 0; k < 64; ++k) s = fmaf(b1[k], rgb_w1[j * 64 + k], s);
        b2[j] = fmaxf(s, 0.f);
    }
    #pragma unroll
    for (int o = 0; o < 3; ++o) {
        float s = 0.f;
        #pragma unroll
        for (int k = 0; k < 64; ++k) s = fmaf(b2[k], rgb_wout[o * 64 + k], s);
        out[n + 3 * i + o] = 1.0f / (1.0f + expf(-s));
    }
}

extern "C" void kernel_launch(void* const* d_in, const int* in_sizes, int n_in,
                              void* d_out, int out_size, void* d_ws, size_t ws_size,
                              hipStream_t stream) {
    const float* x        = (const float*)d_in[0];
    const float* d        = (const float*)d_in[1];
    const float* table    = (const float*)d_in[2];
    const float* xyz_w0   = (const float*)d_in[3];
    const float* xyz_wout = (const float*)d_in[4];
    const float* rgb_w0   = (const float*)d_in[5];
    const float* rgb_w1   = (const float*)d_in[6];
    const float* rgb_wout = (const float*)d_in[7];
    float* out = (float*)d_out;

    int n = in_sizes[0] / 3;

    // resolution table in float64 exactly like numpy (level 14 = 1482.0045;
    // f32 recompute could floor to 1481 and corrupt every level-14 hash)
    ResTable rt;
    double b = std::exp((std::log(2048.0) - std::log(16.0)) / 15.0);
    for (int l = 0; l < NLEVELS; ++l)
        rt.r[l] = (float)std::floor(16.0 * std::pow(b, (double)l));

    size_t emb_bytes = (size_t)n * 32u * sizeof(float);
    if (ws_size >= emb_bytes) {
        float* embT = (float*)d_ws;   // layout (8, N, 4)
        int chunks = (n + 255) / 256;
        hipLaunchKernelGGL(ngp_encode, dim3(chunks * 8), dim3(256), 0, stream,
                           x, table, embT, rt, n);
        hipLaunchKernelGGL(ngp_mlp, dim3(chunks), dim3(256), 0, stream,
                           embT, d, xyz_w0, xyz_wout, rgb_w0, rgb_w1, rgb_wout,
                           out, n);
    } else {
        int blocks = (n + 255) / 256;
        hipLaunchKernelGGL(ngp_fused, dim3(blocks), dim3(256), 0, stream,
                           x, d, table, xyz_w0, xyz_wout, rgb_w0, rgb_w1, rgb_wout,
                           out, rt, n);
    }
}

// Round 3
// 248.583 us; speedup vs baseline: 1.3820x; 1.3820x over previous
//
#include <hip/hip_runtime.h>
#include <cmath>
#include <cstdint>

#define NLEVELS 16
#define LOG2T 19
#define TSIZE (1u << LOG2T)

struct ResTable { float r[NLEVELS]; };

// ---------------------------------------------------------------------------
// Kernel 0: convert f32 table (L,T,2) -> bf16 table in ws, packed one uint32
// per (entry, 2 features). RNE via __float2bfloat16 not needed for accuracy
// (values +-1e-4); use round-to-nearest-even bit trick for determinism.
// ---------------------------------------------------------------------------
__device__ inline uint16_t f32_to_bf16_rne(float f) {
    uint32_t u = __float_as_uint(f);
    uint32_t rounding = 0x7fffu + ((u >> 16) & 1u);
    return (uint16_t)((u + rounding) >> 16);
}

__global__ __launch_bounds__(256) void conv_table(
    const float* __restrict__ t, uint32_t* __restrict__ o, int n_pairs)
{
    int i = blockIdx.x * blockDim.x + threadIdx.x;   // one uint32 (2 feats) out
    if (i >= n_pairs) return;
    float2 v = *reinterpret_cast<const float2*>(t + 2 * (size_t)i);
    uint32_t lo = f32_to_bf16_rne(v.x);
    uint32_t hi = f32_to_bf16_rne(v.y);
    o[i] = lo | (hi << 16);
}

// ---------------------------------------------------------------------------
// Kernel 1: fused gather (bf16 table) + SH + MLPs. One thread per point.
// Gather done in 4-level batches: 32 indices -> 32 independent dword loads
// -> accumulate. ~32 outstanding VMEM ops per wave for latency hiding.
// ---------------------------------------------------------------------------
__global__ __launch_bounds__(256) void ngp_fused(
    const float* __restrict__ x,        // (N,3)
    const float* __restrict__ d,        // (N,3)
    const uint32_t* __restrict__ tbl,   // (L,T) packed bf16x2
    const float* __restrict__ xyz_w0,   // (64,32)
    const float* __restrict__ xyz_wout, // (16,64)
    const float* __restrict__ rgb_w0,   // (64,32)
    const float* __restrict__ rgb_w1,   // (64,64)
    const float* __restrict__ rgb_wout, // (3,64)
    float* __restrict__ out,            // [N] sigma then [N*3] rgb
    ResTable res, int n)
{
    int i = blockIdx.x * blockDim.x + threadIdx.x;
    if (i >= n) return;

    float xn0 = x[3 * i + 0] + 0.5f;
    float xn1 = x[3 * i + 1] + 0.5f;
    float xn2 = x[3 * i + 2] + 0.5f;

    float emb[NLEVELS * 2];

    #pragma unroll
    for (int b = 0; b < 4; ++b) {
        uint32_t idx[32];
        float    wg[32];
        #pragma unroll
        for (int ll = 0; ll < 4; ++ll) {
            int l = b * 4 + ll;
            float r  = res.r[l];
            float p0 = xn0 * r, p1 = xn1 * r, p2 = xn2 * r;
            float f0 = floorf(p0), f1 = floorf(p1), f2 = floorf(p2);
            float fr0 = p0 - f0, fr1 = p1 - f1, fr2 = p2 - f2;
            uint32_t xi0 = (uint32_t)f0, xi1 = (uint32_t)f1, xi2 = (uint32_t)f2;
            uint32_t hx0 = xi0,               hx1 = xi0 + 1u;
            uint32_t hy0 = xi1 * 2654435761u, hy1 = (xi1 + 1u) * 2654435761u;
            uint32_t hz0 = xi2 * 805459861u,  hz1 = (xi2 + 1u) * 805459861u;
            #pragma unroll
            for (int c = 0; c < 8; ++c) {
                uint32_t hx = (c & 4) ? hx1 : hx0;
                uint32_t hy = (c & 2) ? hy1 : hy0;
                uint32_t hz = (c & 1) ? hz1 : hz0;
                idx[ll * 8 + c] = (hx ^ hy ^ hz) & (TSIZE - 1u);
                float wx = (c & 4) ? fr0 : 1.f - fr0;
                float wy = (c & 2) ? fr1 : 1.f - fr1;
                float wz = (c & 1) ? fr2 : 1.f - fr2;
                wg[ll * 8 + c] = wx * wy * wz;
            }
        }
        // issue all 32 loads before any accumulate
        uint32_t val[32];
        #pragma unroll
        for (int ll = 0; ll < 4; ++ll) {
            const uint32_t* tl = tbl + (size_t)(b * 4 + ll) * (size_t)TSIZE;
            #pragma unroll
            for (int c = 0; c < 8; ++c)
                val[ll * 8 + c] = tl[idx[ll * 8 + c]];
        }
        #pragma unroll
        for (int ll = 0; ll < 4; ++ll) {
            float a0 = 0.f, a1 = 0.f;
            #pragma unroll
            for (int c = 0; c < 8; ++c) {
                uint32_t pv = val[ll * 8 + c];
                float v0 = __uint_as_float(pv << 16);
                float v1 = __uint_as_float(pv & 0xffff0000u);
                float w  = wg[ll * 8 + c];
                a0 = fmaf(w, v0, a0);
                a1 = fmaf(w, v1, a1);
            }
            emb[2 * (b * 4 + ll)]     = a0;
            emb[2 * (b * 4 + ll) + 1] = a1;
        }
    }

    // ---- xyz MLP: 32 -> 64 (ReLU) -> 16 (linear)
    float h1[64];
    #pragma unroll
    for (int j = 0; j < 64; ++j) {
        float s = 0.f;
        #pragma unroll
        for (int k = 0; k < 32; ++k) s = fmaf(emb[k], xyz_w0[j * 32 + k], s);
        h1[j] = fmaxf(s, 0.f);
    }
    float hh[16];
    #pragma unroll
    for (int o = 0; o < 16; ++o) {
        float s = 0.f;
        #pragma unroll
        for (int k = 0; k < 64; ++k) s = fmaf(h1[k], xyz_wout[o * 64 + k], s);
        hh[o] = s;
    }
    out[i] = expf(hh[0]);   // sigma

    // ---- SH degree-4
    float dx = d[3 * i + 0], dy = d[3 * i + 1], dz = d[3 * i + 2];
    float inv = rsqrtf(dx * dx + dy * dy + dz * dz);
    float X = dx * inv, Y = dy * inv, Z = dz * inv;
    float xx = X * X, yy = Y * Y, zz = Z * Z;
    float xy = X * Y, yz = Y * Z, xz = X * Z;

    float f[32];
    f[0]  = 0.28209479177387814f;
    f[1]  = -0.4886025119029199f * Y;
    f[2]  =  0.4886025119029199f * Z;
    f[3]  = -0.4886025119029199f * X;
    f[4]  =  1.0925484305920792f * xy;
    f[5]  = -1.0925484305920792f * yz;
    f[6]  =  0.31539156525252005f * (3.0f * zz - 1.0f);
    f[7]  = -1.0925484305920792f * xz;
    f[8]  =  0.5462742152960396f * (xx - yy);
    f[9]  = -0.5900435899266435f * Y * (3.0f * xx - yy);
    f[10] =  2.890611442640554f * xy * Z;
    f[11] = -0.4570457994644658f * Y * (4.0f * zz - xx - yy);
    f[12] =  0.3731763325901154f * Z * (2.0f * zz - 3.0f * xx - 3.0f * yy);
    f[13] = -0.4570457994644658f * X * (4.0f * zz - xx - yy);
    f[14] =  1.445305721320277f * Z * (xx - yy);
    f[15] = -0.5900435899266435f * X * (xx - 3.0f * yy);
    #pragma unroll
    for (int o = 0; o < 16; ++o) f[16 + o] = hh[o];

    // ---- rgb MLP: 32 -> 64 (ReLU) -> 64 (ReLU) -> 3 (sigmoid)
    float b1[64];
    #pragma unroll
    for (int j = 0; j < 64; ++j) {
        float s = 0.f;
        #pragma unroll
        for (int k = 0; k < 32; ++k) s = fmaf(f[k], rgb_w0[j * 32 + k], s);
        b1[j] = fmaxf(s, 0.f);
    }
    float b2[64];
    #pragma unroll
    for (int j = 0; j < 64; ++j) {
        float s = 0.f;
        #pragma unroll
        for (int k = 0; k < 64; ++k) s = fmaf(b1[k], rgb_w1[j * 64 + k], s);
        b2[j] = fmaxf(s, 0.f);
    }
    #pragma unroll
    for (int o = 0; o < 3; ++o) {
        float s = 0.f;
        #pragma unroll
        for (int k = 0; k < 64; ++k) s = fmaf(b2[k], rgb_wout[o * 64 + k], s);
        out[n + 3 * i + o] = 1.0f / (1.0f + expf(-s));
    }
}

// ---------------------------------------------------------------------------
// Fallback (ws too small for bf16 table): round-1 fused f32 kernel.
// ---------------------------------------------------------------------------
__global__ __launch_bounds__(256) void ngp_fused_f32(
    const float* __restrict__ x,
    const float* __restrict__ d,
    const float* __restrict__ table,
    const float* __restrict__ xyz_w0,
    const float* __restrict__ xyz_wout,
    const float* __restrict__ rgb_w0,
    const float* __restrict__ rgb_w1,
    const float* __restrict__ rgb_wout,
    float* __restrict__ out,
    ResTable res, int n)
{
    int i = blockIdx.x * blockDim.x + threadIdx.x;
    if (i >= n) return;

    float xn0 = x[3 * i + 0] + 0.5f;
    float xn1 = x[3 * i + 1] + 0.5f;
    float xn2 = x[3 * i + 2] + 0.5f;

    float emb[NLEVELS * 2];
    #pragma unroll
    for (int l = 0; l < NLEVELS; ++l) {
        float r  = res.r[l];
        float p0 = xn0 * r, p1 = xn1 * r, p2 = xn2 * r;
        float f0 = floorf(p0), f1 = floorf(p1), f2 = floorf(p2);
        float fr0 = p0 - f0, fr1 = p1 - f1, fr2 = p2 - f2;
        uint32_t xi0 = (uint32_t)f0, xi1 = (uint32_t)f1, xi2 = (uint32_t)f2;
        uint32_t hx0 = xi0,               hx1 = xi0 + 1u;
        uint32_t hy0 = xi1 * 2654435761u, hy1 = (xi1 + 1u) * 2654435761u;
        uint32_t hz0 = xi2 * 805459861u,  hz1 = (xi2 + 1u) * 805459861u;
        const float* tl = table + (size_t)l * (size_t)TSIZE * 2u;
        float acc0 = 0.f, acc1 = 0.f;
        #pragma unroll
        for (int c = 0; c < 8; ++c) {
            uint32_t hx = (c & 4) ? hx1 : hx0;
            uint32_t hy = (c & 2) ? hy1 : hy0;
            uint32_t hz = (c & 1) ? hz1 : hz0;
            uint32_t h  = (hx ^ hy ^ hz) & (TSIZE - 1u);
            float wx = (c & 4) ? fr0 : 1.f - fr0;
            float wy = (c & 2) ? fr1 : 1.f - fr1;
            float wz = (c & 1) ? fr2 : 1.f - fr2;
            float w  = wx * wy * wz;
            float2 v = *reinterpret_cast<const float2*>(tl + 2u * h);
            acc0 = fmaf(w, v.x, acc0);
            acc1 = fmaf(w, v.y, acc1);
        }
        emb[2 * l]     = acc0;
        emb[2 * l + 1] = acc1;
    }

    float h1[64];
    #pragma unroll
    for (int j = 0; j < 64; ++j) {
        float s = 0.f;
        #pragma unroll
        for (int k = 0; k < 32; ++k) s = fmaf(emb[k], xyz_w0[j * 32 + k], s);
        h1[j] = fmaxf(s, 0.f);
    }
    float hh[16];
    #pragma unroll
    for (int o = 0; o < 16; ++o) {
        float s = 0.f;
        #pragma unroll
        for (int k = 0; k < 64; ++k) s = fmaf(h1[k], xyz_wout[o * 64 + k], s);
        hh[o] = s;
    }
    out[i] = expf(hh[0]);

    float dx = d[3 * i + 0], dy = d[3 * i + 1], dz = d[3 * i + 2];
    float inv = rsqrtf(dx * dx + dy * dy + dz * dz);
    float X = dx * inv, Y = dy * inv, Z = dz * inv;
    float xx = X * X, yy = Y * Y, zz = Z * Z;
    float xy = X * Y, yz = Y * Z, xz = X * Z;

    float f[32];
    f[0]  = 0.28209479177387814f;
    f[1]  = -0.4886025119029199f * Y;
    f[2]  =  0.4886025119029199f * Z;
    f[3]  = -0.4886025119029199f * X;
    f[4]  =  1.0925484305920792f * xy;
    f[5]  = -1.0925484305920792f * yz;
    f[6]  =  0.31539156525252005f * (3.0f * zz - 1.0f);
    f[7]  = -1.0925484305920792f * xz;
    f[8]  =  0.5462742152960396f * (xx - yy);
    f[9]  = -0.5900435899266435f * Y * (3.0f * xx - yy);
    f[10] =  2.890611442640554f * xy * Z;
    f[11] = -0.4570457994644658f * Y * (4.0f * zz - xx - yy);
    f[12] =  0.3731763325901154f * Z * (2.0f * zz - 3.0f * xx - 3.0f * yy);
    f[13] = -0.4570457994644658f * X * (4.0f * zz - xx - yy);
    f[14] =  1.445305721320277f * Z * (xx - yy);
    f[15] = -0.5900435899266435f * X * (xx - 3.0f * yy);
    #pragma unroll
    for (int o = 0; o < 16; ++o) f[16 + o] = hh[o];

    float b1[64];
    #pragma unroll
    for (int j = 0; j < 64; ++j) {
        float s = 0.f;
        #pragma unroll
        for (int k = 0; k < 32; ++k) s = fmaf(f[k], rgb_w0[j * 32 + k], s);
        b1[j] = fmaxf(s, 0.f);
    }
    float b2[64];
    #pragma unroll
    for (int j = 0; j < 64; ++j) {
        float s = 0.f;
        #pragma unroll
        for (int k = 0; k < 64; ++k) s = fmaf(b1[k], rgb_w1[j * 64 + k], s);
        b2[j] = fmaxf(s, 0.f);
    }
    #pragma unroll
    for (int o = 0; o < 3; ++o) {
        float s = 0.f;
        #pragma unroll
        for (int k = 0; k < 64; ++k) s = fmaf(b2[k], rgb_wout[o * 64 + k], s);
        out[n + 3 * i + o] = 1.0f / (1.0f + expf(-s));
    }
}

extern "C" void kernel_launch(void* const* d_in, const int* in_sizes, int n_in,
                              void* d_out, int out_size, void* d_ws, size_t ws_size,
                              hipStream_t stream) {
    const float* x        = (const float*)d_in[0];
    const float* d        = (const float*)d_in[1];
    const float* table    = (const float*)d_in[2];
    const float* xyz_w0   = (const float*)d_in[3];
    const float* xyz_wout = (const float*)d_in[4];
    const float* rgb_w0   = (const float*)d_in[5];
    const float* rgb_w1   = (const float*)d_in[6];
    const float* rgb_wout = (const float*)d_in[7];
    float* out = (float*)d_out;

    int n = in_sizes[0] / 3;

    // resolution table in float64 exactly like numpy (level 14 = 1482.0045;
    // f32 recompute could floor to 1481 and corrupt every level-14 hash)
    ResTable rt;
    double b = std::exp((std::log(2048.0) - std::log(16.0)) / 15.0);
    for (int l = 0; l < NLEVELS; ++l)
        rt.r[l] = (float)std::floor(16.0 * std::pow(b, (double)l));

    int n_pairs = NLEVELS * TSIZE;                 // one uint32 per (entry,2feat)
    size_t tbl_bytes = (size_t)n_pairs * 4u;       // 33.5 MB

    int blocks = (n + 255) / 256;
    if (ws_size >= tbl_bytes) {
        uint32_t* tbl16 = (uint32_t*)d_ws;
        int cb = (n_pairs + 255) / 256;
        hipLaunchKernelGGL(conv_table, dim3(cb), dim3(256), 0, stream,
                           table, tbl16, n_pairs);
        hipLaunchKernelGGL(ngp_fused, dim3(blocks), dim3(256), 0, stream,
                           x, d, tbl16, xyz_w0, xyz_wout, rgb_w0, rgb_w1,
                           rgb_wout, out, rt, n);
    } else {
        hipLaunchKernelGGL(ngp_fused_f32, dim3(blocks), dim3(256), 0, stream,
                           x, d, table, xyz_w0, xyz_wout, rgb_w0, rgb_w1,
                           rgb_wout, out, rt, n);
    }
}